// Round 17
// baseline (120.682 us; speedup 1.0000x reference)
//
#include <hip/hip_runtime.h>
#include <hip/hip_bf16.h>

// SNNDecode: z = x @ W^T  (einsum 'bsh,oh->sbo'), then linear LI scan over seq.
//   v_t = v_{t-1} + a*(i_{t-1} - v_{t-1});  i_t = (1-b)*i_{t-1} + z_t;  out[t]=v_t
// d_out = [voltages (2048*64*128)] ++ [v_f (8192)] ++ [i_f (8192)]  (fp32)
//
// Round 17: R10 champion (104.2 us, best of 16 rounds) minus TWO launches:
//  - k_wconv deleted: B fragments load straight from fp32 W (L2-resident
//    256 KB); raw f4 loads issued BEFORE the deep xa prefetch (keeps the
//    in-order vmcnt discipline), cvt_pk at consumption (+32 VALU/step vs ~6%
//    VALUBusy -- free).
//  - phase 2 stays R10's single k_emit (per-thread prefix; measured equal to
//    the separate k_comb within noise).
// Everything else byte-identical to the champion: BK=64 ring-3 reg-staged
// gemm, f32 ZS epilogue, fused chunk scans, bf16 z in ws (ZB=1) with f32
// fallback. 2 dispatches total.
// ws: [0,4M) vend|iend [64][8192] | [4M+128K,+32M) z bf16 (offset kept).

typedef __attribute__((ext_vector_type(4))) float          f4;
typedef __attribute__((ext_vector_type(8))) short          s8;
typedef __attribute__((ext_vector_type(4))) unsigned       u4;
typedef __attribute__((ext_vector_type(2))) unsigned       u2;
typedef __attribute__((ext_vector_type(4))) unsigned short su4;

#define SEQ    2048
#define HID    512
#define CHAINS 8192          // batch(64) * out(128)
#define VOLT   16777216      // SEQ * CHAINS
#define NCH    64            // SEQ / 32
#define CHUNK  32

__device__ __forceinline__ float clamp01(float x) { return fminf(fmaxf(x, 0.f), 1.f); }

// packed fp32x2 -> bf16x2 (RNE) as one u32; compiler emits v_cvt_pk_bf16_f32
__device__ __forceinline__ unsigned pkbf(float x, float y) {
  float2 t; t.x = x; t.y = y;
  union { __hip_bfloat162 h; unsigned u; } c;
  c.h = __float22bfloat162_rn(t);
  return c.u;
}

__device__ __forceinline__ float bf2f(unsigned short s) {
  union { unsigned u; float f; } c; c.u = ((unsigned)s) << 16; return c.f;
}

// LDS swizzle (ushort-index units): conflict-free for both ds_write_b128
// staging and ds_read_b128 fragment reads (round-1-verified).
__device__ __forceinline__ int swz(int row, int k) {
  return (row * 64 + k) ^ ((row & 7) << 3);
}

// ---------------- Phase 1 (+2a): GEMM tile + z store + fused chunk scans ---
// ZB=1: z stored bf16 in zbf.  ZB=0: z stored f32 in Out (fallback).
template <int ZB>
__global__ __launch_bounds__(256, 2) void k_gemm(const float* __restrict__ X,
                                                 const float* __restrict__ W,
                                                 float* __restrict__ Out,
                                                 unsigned short* __restrict__ zbf,
                                                 const float* __restrict__ tau_syn,
                                                 const float* __restrict__ tau_mem,
                                                 float* __restrict__ ws) {
  __shared__ __align__(16) char smem[65536];
  short* const AS = (short*)smem;            // [2][128][64] bf16 A tiles (32 KB)
  float* const ZS = (float*)smem;            // [128][128] f32 z tile (aliased)

  const int tid = threadIdx.x;
  const int blk = blockIdx.x;
  const int m0  = blk << 7;          // global row = b*2048 + t
  const int bI  = blk >> 4;          // batch index
  const int t0  = (blk & 15) << 7;   // t tile base

  const int rbase = tid >> 3;        // 0..31: staging row group
  const int coff  = (tid & 7) << 3;  // staging k offset (8 elems)

  const int lane = tid & 63;
  const int wid  = tid >> 6;
  const int wmb  = (wid >> 1) << 6;  // wave row base: 0/64
  const int wnb  = (wid & 1) << 6;   // wave col base: 0/64
  const int lr   = lane & 15;
  const int lk   = (lane >> 4) << 3;

  const float* pX[4];
#pragma unroll
  for (int c = 0; c < 4; ++c)
    pX[c] = X + (size_t)(m0 + (c << 5) + rbase) * HID + coff;
  const float* pW[4];                // fp32 W, L2-resident (no pre-conversion)
#pragma unroll
  for (int ni = 0; ni < 4; ++ni)
    pW[ni] = W + (size_t)(wnb + (ni << 4) + lr) * HID + lk;

  f4 acc[4][4];
#pragma unroll
  for (int mi = 0; mi < 4; ++mi)
#pragma unroll
    for (int ni = 0; ni < 4; ++ni) acc[mi][ni] = (f4){0.f, 0.f, 0.f, 0.f};

  // A register prefetch: ring of 3 (2 steps ahead); static indices via unroll.
  f4 xa[3][4][2];
#pragma unroll
  for (int c = 0; c < 4; ++c) {
    xa[0][c][0] = *(const f4*)(pX[c]);
    xa[0][c][1] = *(const f4*)(pX[c] + 4);
    xa[1][c][0] = *(const f4*)(pX[c] + 64);
    xa[1][c][1] = *(const f4*)(pX[c] + 68);
  }

#pragma unroll
  for (int ks = 0; ks < 8; ++ks) {
    const int cur = ks % 3;
    short* const Ac = AS + ((ks & 1) << 13);
    // Stage current A tile into LDS (consumes xa[cur] = oldest outstanding
    // loads; deeper prefetch stays in flight through the wait).
#pragma unroll
    for (int c = 0; c < 4; ++c) {
      const int row = (c << 5) + rbase;
      u4 va;
      va[0] = pkbf(xa[cur][c][0][0], xa[cur][c][0][1]);
      va[1] = pkbf(xa[cur][c][0][2], xa[cur][c][0][3]);
      va[2] = pkbf(xa[cur][c][1][0], xa[cur][c][1][1]);
      va[3] = pkbf(xa[cur][c][1][2], xa[cur][c][1][3]);
      *(u4*)&Ac[swz(row, coff)] = va;
    }
    __syncthreads();
    // B fragments (fp32, L2) issued BEFORE the deep xa prefetch so their
    // vmcnt-consume (in-order) doesn't drain the xa loads. Raw loads here;
    // cvt_pk at consumption.
    f4 wg[2][4][2];
#pragma unroll
    for (int kk = 0; kk < 2; ++kk)
#pragma unroll
      for (int ni = 0; ni < 4; ++ni) {
        wg[kk][ni][0] = *(const f4*)(pW[ni] + (ks << 6) + (kk << 5));
        wg[kk][ni][1] = *(const f4*)(pW[ni] + (ks << 6) + (kk << 5) + 4);
      }
    // Deep prefetch: A tile for step ks+2.
    if (ks < 6) {
      const int k0 = (ks + 2) << 6;
      const int nxt = (ks + 2) % 3;
#pragma unroll
      for (int c = 0; c < 4; ++c) {
        xa[nxt][c][0] = *(const f4*)(pX[c] + k0);
        xa[nxt][c][1] = *(const f4*)(pX[c] + k0 + 4);
      }
    }
#pragma unroll
    for (int kk = 0; kk < 2; ++kk) {
      s8 af[4], bg[4];
#pragma unroll
      for (int mi = 0; mi < 4; ++mi)
        af[mi] = *(const s8*)&Ac[swz(wmb + (mi << 4) + lr, (kk << 5) + lk)];
#pragma unroll
      for (int ni = 0; ni < 4; ++ni) {
        union { u4 u; s8 s; } t;
        t.u[0] = pkbf(wg[kk][ni][0][0], wg[kk][ni][0][1]);
        t.u[1] = pkbf(wg[kk][ni][0][2], wg[kk][ni][0][3]);
        t.u[2] = pkbf(wg[kk][ni][1][0], wg[kk][ni][1][1]);
        t.u[3] = pkbf(wg[kk][ni][1][2], wg[kk][ni][1][3]);
        bg[ni] = t.s;
      }
#pragma unroll
      for (int mi = 0; mi < 4; ++mi)
#pragma unroll
        for (int ni = 0; ni < 4; ++ni)
          acc[mi][ni] = __builtin_amdgcn_mfma_f32_16x16x32_bf16(af[mi], bg[ni],
                                                                acc[mi][ni], 0, 0, 0);
    }
  }

  // ---- Epilogue: park z tile in LDS (aliases dead staging buffer) ----
  __syncthreads();   // all waves done reading AS
  const int rr = (lane >> 4) << 2;
#pragma unroll
  for (int mi = 0; mi < 4; ++mi)
#pragma unroll
    for (int ni = 0; ni < 4; ++ni)
#pragma unroll
      for (int r = 0; r < 4; ++r)
        ZS[(wmb + (mi << 4) + rr + r) * 128 + wnb + (ni << 4) + lr] = acc[mi][ni][r];
  __syncthreads();

  // (a) stream z tile out
  if (ZB) {
    unsigned short* const Zrow = zbf + (size_t)t0 * 8192 + (bI << 7);
#pragma unroll
    for (int i = 0; i < 16; ++i) {
      const int idx  = (i << 8) + tid;
      const int toff = idx >> 5;
      const int c4   = idx & 31;
      const f4 zv = *(const f4*)&ZS[toff * 128 + (c4 << 2)];
      u2 pk; pk[0] = pkbf(zv[0], zv[1]); pk[1] = pkbf(zv[2], zv[3]);
      *(u2*)(Zrow + (size_t)toff * 8192 + (c4 << 2)) = pk;
    }
  } else {
    float* const Zrow = Out + (size_t)t0 * 8192 + (bI << 7);
#pragma unroll
    for (int i = 0; i < 16; ++i) {
      const int idx  = (i << 8) + tid;
      const int toff = idx >> 5;
      const int c4   = idx & 31;
      *(f4*)(Zrow + (size_t)toff * 8192 + (c4 << 2)) = *(const f4*)&ZS[toff * 128 + (c4 << 2)];
    }
  }
  // (b) fused phase 2a: zero-state scans of the FOUR 32-chunks this block owns
  {
    const float a  = 0.001f * clamp01(tau_mem[0]);
    const float eb = 1.f - 0.001f * clamp01(tau_syn[0]);
    const int col = tid & 127, h = tid >> 7;
    const int chain = (bI << 7) + col;
#pragma unroll
    for (int s = 0; s < 2; ++s) {
      const int r0 = (h << 6) + (s << 5);
      const float* zs = ZS + r0 * 128 + col;   // bank=col&31: 2-way (free)
      float v = 0.f, ii = 0.f;
#pragma unroll 8
      for (int j = 0; j < CHUNK; ++j) {
        const float z = zs[j * 128];
        v  = v + a * (ii - v);
        ii = eb * ii + z;
      }
      const int q = ((blk & 15) << 2) + (h << 1) + s;   // chunk 0..63
      ws[q * CHAINS + chain]                 = v;   // vend
      ws[NCH * CHAINS + q * CHAINS + chain]  = ii;  // iend
    }
  }
}

// ---------------- Phase 2 (fused combine + emit): each thread reconstructs
// its chunk in-state from the end-state prefix (independent loads, closed-form
// M^32), scans 32 steps writing v to Out; q==63 writes finals.
template <int ZB>
__global__ __launch_bounds__(256) void k_emit(const float* __restrict__ tau_syn,
                                              const float* __restrict__ tau_mem,
                                              float* __restrict__ Out,
                                              const unsigned short* __restrict__ zbf,
                                              const float* __restrict__ ws) {
  const int tid = threadIdx.x;
  const int cg = (blockIdx.x & 31) * 64 + (tid & 63);  // f4 chain-group 0..2047
  const int q  = (blockIdx.x >> 5) * 4 + (tid >> 6);   // chunk 0..63 (wave-uniform)
  const float a  = 0.001f * clamp01(tau_mem[0]);
  const float bb = 0.001f * clamp01(tau_syn[0]);
  const float ea = 1.f - a, eb = 1.f - bb;
  // M^32 first row [P,Q]; [M^32]_11 = R
  float P = 1.f, Q = 0.f, R = 1.f;
#pragma unroll
  for (int j = 0; j < CHUNK; ++j) { float Pn = P * ea; Q = P * a + Q * eb; P = Pn; R *= eb; }

  const f4* vend = (const f4*)ws;          // [64][2048]
  const f4* iend = vend + NCH * 2048;
  f4 sv = (f4){0.f, 0.f, 0.f, 0.f}, si = (f4){0.f, 0.f, 0.f, 0.f};
#pragma unroll 4
  for (int p = 0; p < q; ++p) {            // independent, pipelineable loads
    const f4 ve = vend[p * 2048 + cg];
    const f4 ie = iend[p * 2048 + cg];
    const f4 nv = P * sv + Q * si + ve;
    si = R * si + ie;
    sv = nv;
  }

  f4* o4 = (f4*)Out;
  const int tb = q << 5;
  f4 v = sv, ii = si;
#pragma unroll 8
  for (int j = 0; j < CHUNK; ++j) {
    const size_t idx = (size_t)(tb + j) * 2048 + cg;
    f4 z;
    if (ZB) {
      const su4 zb = *(const su4*)(zbf + (((size_t)(tb + j)) << 13) + (cg << 2));
      z[0] = bf2f(zb[0]); z[1] = bf2f(zb[1]); z[2] = bf2f(zb[2]); z[3] = bf2f(zb[3]);
    } else {
      z = o4[idx];
    }
    v  = v + a * (ii - v);
    o4[idx] = v;
    ii = eb * ii + z;
  }
  if (q == NCH - 1) {
    ((f4*)(Out + VOLT))[cg]          = v;    // v_f
    ((f4*)(Out + VOLT + CHAINS))[cg] = ii;   // i_f
  }
}

extern "C" void kernel_launch(void* const* d_in, const int* in_sizes, int n_in,
                              void* d_out, int out_size, void* d_ws, size_t ws_size,
                              hipStream_t stream) {
  const float* X   = (const float*)d_in[0];  // [64][2048][512]
  const float* W   = (const float*)d_in[1];  // [128][512]
  const float* tsy = (const float*)d_in[2];
  const float* tme = (const float*)d_in[3];
  float* Out = (float*)d_out;
  float* ws  = (float*)d_ws;
  unsigned short* zbf = (unsigned short*)((char*)d_ws + (4u << 20) + (128u << 10));
  const size_t need = (4ull << 20) + (128ull << 10) + (32ull << 20);

  if (ws_size >= need) {
    k_gemm<1><<<1024, 256, 0, stream>>>(X, W, Out, zbf, tsy, tme, ws);
    k_emit<1><<<512, 256, 0, stream>>>(tsy, tme, Out, zbf, ws);
  } else {
    k_gemm<0><<<1024, 256, 0, stream>>>(X, W, Out, zbf, tsy, tme, ws);
    k_emit<0><<<512, 256, 0, stream>>>(tsy, tme, Out, zbf, ws);
  }
}

// Round 18
// 104.419 us; speedup vs baseline: 1.1558x; 1.1558x over previous
//
#include <hip/hip_runtime.h>
#include <hip/hip_bf16.h>

// SNNDecode: z = x @ W^T  (einsum 'bsh,oh->sbo'), then linear LI scan over seq.
//   v_t = v_{t-1} + a*(i_{t-1} - v_{t-1});  i_t = (1-b)*i_{t-1} + z_t;  out[t]=v_t
// d_out = [voltages (2048*64*128)] ++ [v_f (8192)] ++ [i_f (8192)]  (fp32)
//
// FINAL (round 18): the round-10 champion restored verbatim -- best measured
// configuration over 17 rounds (104.2 us, absmax 0.25). Structure:
//   k_wconv: W -> bf16 side buffer (128 KB, L2-resident).
//   k_gemm:  128x128 tile, BK=64, reg-staged ring-3 A prefetch with
//            post-barrier issue (loads in flight under ds_read+MFMA), B
//            fragments direct from L2 bf16 W, fused zero-state chunk scans
//            in the f32 LDS z-tile epilogue; z stored bf16 in ws (ZB=1).
//   k_emit:  per-thread prefix combine over chunk end-states (independent
//            loads) + 32-step re-scan writing v; q==63 emits v_f/i_f.
// Verified plateau: 7 structural alternatives (no-LDS R2/R13, coop R8,
// manual grid barrier R9, occupancy x2 R11/R14, BK=128 R15, DMA staging R16,
// wconv-fusion R17) all regressed or were neutral; the K-loop sits near the
// 2-waves/SIMD register envelope and any +64-VGPR working set spills.
// ws: [0,4M) vend|iend [64][8192] | [4M,+128K) bf16 W | [4M+128K,+32M) z bf16.

typedef __attribute__((ext_vector_type(4))) float          f4;
typedef __attribute__((ext_vector_type(8))) short          s8;
typedef __attribute__((ext_vector_type(4))) unsigned       u4;
typedef __attribute__((ext_vector_type(2))) unsigned       u2;
typedef __attribute__((ext_vector_type(4))) unsigned short su4;

#define SEQ    2048
#define HID    512
#define CHAINS 8192          // batch(64) * out(128)
#define VOLT   16777216      // SEQ * CHAINS
#define NCH    64            // SEQ / 32
#define CHUNK  32

__device__ __forceinline__ float clamp01(float x) { return fminf(fmaxf(x, 0.f), 1.f); }

// packed fp32x2 -> bf16x2 (RNE) as one u32; compiler emits v_cvt_pk_bf16_f32
__device__ __forceinline__ unsigned pkbf(float x, float y) {
  float2 t; t.x = x; t.y = y;
  union { __hip_bfloat162 h; unsigned u; } c;
  c.h = __float22bfloat162_rn(t);
  return c.u;
}

__device__ __forceinline__ short f2bf(float f) {
  union { float f; unsigned u; } c; c.f = f;
  unsigned u = c.u;
  unsigned r = (u + 0x7fffu + ((u >> 16) & 1u)) >> 16;
  return (short)r;
}

__device__ __forceinline__ float bf2f(unsigned short s) {
  union { unsigned u; float f; } c; c.u = ((unsigned)s) << 16; return c.f;
}

// LDS swizzle (ushort-index units): conflict-free for both ds_write_b128
// staging and ds_read_b128 fragment reads (round-1-verified).
__device__ __forceinline__ int swz(int row, int k) {
  return (row * 64 + k) ^ ((row & 7) << 3);
}

// ---------------- Phase 0: W (fp32 [128][512]) -> bf16 in ws ---------------
__global__ __launch_bounds__(256) void k_wconv(const float* __restrict__ W,
                                               unsigned short* __restrict__ Wb) {
  const int i = blockIdx.x * 256 + threadIdx.x;
  const f4 lo = ((const f4*)W)[2 * i];
  const f4 hi = ((const f4*)W)[2 * i + 1];
  s8 v;
#pragma unroll
  for (int j = 0; j < 4; ++j) { v[j] = f2bf(lo[j]); v[j + 4] = f2bf(hi[j]); }
  ((s8*)Wb)[i] = v;
}

// ---------------- Phase 1 (+2a): GEMM tile + z store + fused chunk scans ---
// ZB=1: z stored bf16 in zbf.  ZB=0: z stored f32 in Out (round-6 fallback).
template <int ZB>
__global__ __launch_bounds__(256, 2) void k_gemm(const float* __restrict__ X,
                                                 const unsigned short* __restrict__ Wb,
                                                 float* __restrict__ Out,
                                                 unsigned short* __restrict__ zbf,
                                                 const float* __restrict__ tau_syn,
                                                 const float* __restrict__ tau_mem,
                                                 float* __restrict__ ws) {
  __shared__ __align__(16) char smem[65536];
  short* const AS = (short*)smem;            // [2][128][64] bf16 A tiles (32 KB)
  float* const ZS = (float*)smem;            // [128][128] f32 z tile (aliased)

  const int tid = threadIdx.x;
  const int blk = blockIdx.x;
  const int m0  = blk << 7;          // global row = b*2048 + t
  const int bI  = blk >> 4;          // batch index
  const int t0  = (blk & 15) << 7;   // t tile base

  const int rbase = tid >> 3;        // 0..31: staging row group
  const int coff  = (tid & 7) << 3;  // staging k offset (8 elems)

  const int lane = tid & 63;
  const int wid  = tid >> 6;
  const int wmb  = (wid >> 1) << 6;  // wave row base: 0/64
  const int wnb  = (wid & 1) << 6;   // wave col base: 0/64
  const int lr   = lane & 15;
  const int lk   = (lane >> 4) << 3;

  const float* pX[4];
#pragma unroll
  for (int c = 0; c < 4; ++c)
    pX[c] = X + (size_t)(m0 + (c << 5) + rbase) * HID + coff;
  const unsigned short* pB[4];
#pragma unroll
  for (int ni = 0; ni < 4; ++ni)
    pB[ni] = Wb + (size_t)(wnb + (ni << 4) + lr) * HID + lk;

  f4 acc[4][4];
#pragma unroll
  for (int mi = 0; mi < 4; ++mi)
#pragma unroll
    for (int ni = 0; ni < 4; ++ni) acc[mi][ni] = (f4){0.f, 0.f, 0.f, 0.f};

  // A register prefetch: ring of 3 (2 steps ahead); static indices via unroll.
  f4 xa[3][4][2];
#pragma unroll
  for (int c = 0; c < 4; ++c) {
    xa[0][c][0] = *(const f4*)(pX[c]);
    xa[0][c][1] = *(const f4*)(pX[c] + 4);
    xa[1][c][0] = *(const f4*)(pX[c] + 64);
    xa[1][c][1] = *(const f4*)(pX[c] + 68);
  }

#pragma unroll
  for (int ks = 0; ks < 8; ++ks) {
    const int cur = ks % 3;
    short* const Ac = AS + ((ks & 1) << 13);
    // Stage current A tile into LDS (consumes xa[cur] = oldest outstanding
    // loads; deeper prefetch stays in flight through the wait).
#pragma unroll
    for (int c = 0; c < 4; ++c) {
      const int row = (c << 5) + rbase;
      u4 va;
      va[0] = pkbf(xa[cur][c][0][0], xa[cur][c][0][1]);
      va[1] = pkbf(xa[cur][c][0][2], xa[cur][c][0][3]);
      va[2] = pkbf(xa[cur][c][1][0], xa[cur][c][1][1]);
      va[3] = pkbf(xa[cur][c][1][2], xa[cur][c][1][3]);
      *(u4*)&Ac[swz(row, coff)] = va;
    }
    __syncthreads();
    // B fragments for this step (L2-resident W), issued BEFORE the deep xa
    // prefetch so their vmcnt-consume (in-order) doesn't drain the xa loads.
    s8 bg[2][4];
#pragma unroll
    for (int kk = 0; kk < 2; ++kk)
#pragma unroll
      for (int ni = 0; ni < 4; ++ni)
        bg[kk][ni] = *(const s8*)(pB[ni] + (ks << 6) + (kk << 5));
    // Deep prefetch: A tile for step ks+2.
    if (ks < 6) {
      const int k0 = (ks + 2) << 6;
      const int nxt = (ks + 2) % 3;
#pragma unroll
      for (int c = 0; c < 4; ++c) {
        xa[nxt][c][0] = *(const f4*)(pX[c] + k0);
        xa[nxt][c][1] = *(const f4*)(pX[c] + k0 + 4);
      }
    }
#pragma unroll
    for (int kk = 0; kk < 2; ++kk) {
      s8 af[4];
#pragma unroll
      for (int mi = 0; mi < 4; ++mi)
        af[mi] = *(const s8*)&Ac[swz(wmb + (mi << 4) + lr, (kk << 5) + lk)];
#pragma unroll
      for (int mi = 0; mi < 4; ++mi)
#pragma unroll
        for (int ni = 0; ni < 4; ++ni)
          acc[mi][ni] = __builtin_amdgcn_mfma_f32_16x16x32_bf16(af[mi], bg[kk][ni],
                                                                acc[mi][ni], 0, 0, 0);
    }
  }

  // ---- Epilogue: park z tile in LDS (aliases dead staging buffer) ----
  __syncthreads();   // all waves done reading AS
  const int rr = (lane >> 4) << 2;
#pragma unroll
  for (int mi = 0; mi < 4; ++mi)
#pragma unroll
    for (int ni = 0; ni < 4; ++ni)
#pragma unroll
      for (int r = 0; r < 4; ++r)
        ZS[(wmb + (mi << 4) + rr + r) * 128 + wnb + (ni << 4) + lr] = acc[mi][ni][r];
  __syncthreads();

  // (a) stream z tile out
  if (ZB) {
    unsigned short* const Zrow = zbf + (size_t)t0 * 8192 + (bI << 7);
#pragma unroll
    for (int i = 0; i < 16; ++i) {
      const int idx  = (i << 8) + tid;
      const int toff = idx >> 5;
      const int c4   = idx & 31;
      const f4 zv = *(const f4*)&ZS[toff * 128 + (c4 << 2)];
      u2 pk; pk[0] = pkbf(zv[0], zv[1]); pk[1] = pkbf(zv[2], zv[3]);
      *(u2*)(Zrow + (size_t)toff * 8192 + (c4 << 2)) = pk;
    }
  } else {
    float* const Zrow = Out + (size_t)t0 * 8192 + (bI << 7);
#pragma unroll
    for (int i = 0; i < 16; ++i) {
      const int idx  = (i << 8) + tid;
      const int toff = idx >> 5;
      const int c4   = idx & 31;
      *(f4*)(Zrow + (size_t)toff * 8192 + (c4 << 2)) = *(const f4*)&ZS[toff * 128 + (c4 << 2)];
    }
  }
  // (b) fused phase 2a: zero-state scans of the FOUR 32-chunks this block owns
  {
    const float a  = 0.001f * clamp01(tau_mem[0]);
    const float eb = 1.f - 0.001f * clamp01(tau_syn[0]);
    const int col = tid & 127, h = tid >> 7;
    const int chain = (bI << 7) + col;
#pragma unroll
    for (int s = 0; s < 2; ++s) {
      const int r0 = (h << 6) + (s << 5);
      const float* zs = ZS + r0 * 128 + col;   // bank=col&31: 2-way (free)
      float v = 0.f, ii = 0.f;
#pragma unroll 8
      for (int j = 0; j < CHUNK; ++j) {
        const float z = zs[j * 128];
        v  = v + a * (ii - v);
        ii = eb * ii + z;
      }
      const int q = ((blk & 15) << 2) + (h << 1) + s;   // chunk 0..63
      ws[q * CHAINS + chain]                 = v;   // vend
      ws[NCH * CHAINS + q * CHAINS + chain]  = ii;  // iend
    }
  }
}

// ---------------- Phase 2 (fused combine + emit): each thread reconstructs
// its chunk in-state from the end-state prefix (independent loads, closed-form
// M^32), scans 32 steps writing v to Out; q==63 writes finals.
template <int ZB>
__global__ __launch_bounds__(256) void k_emit(const float* __restrict__ tau_syn,
                                              const float* __restrict__ tau_mem,
                                              float* __restrict__ Out,
                                              const unsigned short* __restrict__ zbf,
                                              const float* __restrict__ ws) {
  const int tid = threadIdx.x;
  const int cg = (blockIdx.x & 31) * 64 + (tid & 63);  // f4 chain-group 0..2047
  const int q  = (blockIdx.x >> 5) * 4 + (tid >> 6);   // chunk 0..63 (wave-uniform)
  const float a  = 0.001f * clamp01(tau_mem[0]);
  const float bb = 0.001f * clamp01(tau_syn[0]);
  const float ea = 1.f - a, eb = 1.f - bb;
  // M^32 first row [P,Q]; [M^32]_11 = R
  float P = 1.f, Q = 0.f, R = 1.f;
#pragma unroll
  for (int j = 0; j < CHUNK; ++j) { float Pn = P * ea; Q = P * a + Q * eb; P = Pn; R *= eb; }

  const f4* vend = (const f4*)ws;          // [64][2048]
  const f4* iend = vend + NCH * 2048;
  f4 sv = (f4){0.f, 0.f, 0.f, 0.f}, si = (f4){0.f, 0.f, 0.f, 0.f};
#pragma unroll 4
  for (int p = 0; p < q; ++p) {            // independent, pipelineable loads
    const f4 ve = vend[p * 2048 + cg];
    const f4 ie = iend[p * 2048 + cg];
    const f4 nv = P * sv + Q * si + ve;
    si = R * si + ie;
    sv = nv;
  }

  f4* o4 = (f4*)Out;
  const int tb = q << 5;
  f4 v = sv, ii = si;
#pragma unroll 8
  for (int j = 0; j < CHUNK; ++j) {
    const size_t idx = (size_t)(tb + j) * 2048 + cg;
    f4 z;
    if (ZB) {
      const su4 zb = *(const su4*)(zbf + (((size_t)(tb + j)) << 13) + (cg << 2));
      z[0] = bf2f(zb[0]); z[1] = bf2f(zb[1]); z[2] = bf2f(zb[2]); z[3] = bf2f(zb[3]);
    } else {
      z = o4[idx];
    }
    v  = v + a * (ii - v);
    o4[idx] = v;
    ii = eb * ii + z;
  }
  if (q == NCH - 1) {
    ((f4*)(Out + VOLT))[cg]          = v;    // v_f
    ((f4*)(Out + VOLT + CHAINS))[cg] = ii;   // i_f
  }
}

extern "C" void kernel_launch(void* const* d_in, const int* in_sizes, int n_in,
                              void* d_out, int out_size, void* d_ws, size_t ws_size,
                              hipStream_t stream) {
  const float* X   = (const float*)d_in[0];  // [64][2048][512]
  const float* W   = (const float*)d_in[1];  // [128][512]
  const float* tsy = (const float*)d_in[2];
  const float* tme = (const float*)d_in[3];
  float* Out = (float*)d_out;
  float* ws  = (float*)d_ws;
  unsigned short* Wb  = (unsigned short*)((char*)d_ws + (4u << 20));
  unsigned short* zbf = (unsigned short*)((char*)d_ws + (4u << 20) + (128u << 10));
  const size_t need = (4ull << 20) + (128ull << 10) + (32ull << 20);

  k_wconv<<<32, 256, 0, stream>>>(W, Wb);
  if (ws_size >= need) {
    k_gemm<1><<<1024, 256, 0, stream>>>(X, Wb, Out, zbf, tsy, tme, ws);
    k_emit<1><<<512, 256, 0, stream>>>(tsy, tme, Out, zbf, ws);
  } else {
    k_gemm<0><<<1024, 256, 0, stream>>>(X, Wb, Out, zbf, tsy, tme, ws);
    k_emit<0><<<512, 256, 0, stream>>>(tsy, tme, Out, zbf, ws);
  }
}